// Round 1
// baseline (1191.966 us; speedup 1.0000x reference)
//
#include <hip/hip_runtime.h>
#include <stdint.h>

// ---------------------------------------------------------------------------
// GraphAggregator: fused 3-layer MLP (256->512->512->128) + SiLU + segment-sum
// Strategy: bf16 MFMA (16x16x32), one block = 32 node rows, everything in LDS.
// Weights pre-packed into MFMA B-fragment order each launch (d_ws, ~897 KB).
// ---------------------------------------------------------------------------

typedef short bf16x8 __attribute__((ext_vector_type(8)));   // 8 bf16 = 4 VGPRs
typedef float f32x4  __attribute__((ext_vector_type(4)));

#define N_NODES   500000
#define BM        32
#define N_BLOCKS  (N_NODES / BM)      // 15625 exactly, no remainder
#define N_GRAPHS  1024
#define N_OUT     128

// packed-weight offsets in bf16 elements inside d_ws
#define W1P_ELEMS (256*512)           // 131072
#define W2P_ELEMS (512*512)           // 262144
#define W3P_ELEMS (512*128)           // 65536
#define W2P_OFF   (W1P_ELEMS)
#define W3P_OFF   (W1P_ELEMS + W2P_ELEMS)
#define PREPACK_THREADS ((W1P_ELEMS + W2P_ELEMS + W3P_ELEMS) / 8)  // 57344

__device__ __forceinline__ short f2bf(float x) {
    // round-to-nearest-even fp32 -> bf16 (inputs are finite)
    uint32_t u = __float_as_uint(x);
    u += 0x7fffu + ((u >> 16) & 1u);
    return (short)(u >> 16);
}

// Pack W[K][N] (row-major fp32) into per-(ntile,ktile) MFMA B fragments:
// dst[((nt*Ktiles + kt)*64 + lane)*8 + j] = bf16( W[kt*32 + (lane>>4)*8 + j][nt*16 + (lane&15)] )
__global__ void prepack_weights(const float* __restrict__ W1,
                                const float* __restrict__ W2,
                                const float* __restrict__ W3,
                                short* __restrict__ wp) {
    int tid = blockIdx.x * blockDim.x + threadIdx.x;
    if (tid >= PREPACK_THREADS) return;
    const float* src; int N, kmask, kshift, dstoff, local;
    if (tid < 16384) {              // W1: K=256 (8 ktiles), N=512
        src = W1; N = 512; kmask = 7;  kshift = 3; dstoff = 0;       local = tid;
    } else if (tid < 49152) {       // W2: K=512 (16 ktiles), N=512
        src = W2; N = 512; kmask = 15; kshift = 4; dstoff = W2P_OFF; local = tid - 16384;
    } else {                        // W3: K=512 (16 ktiles), N=128
        src = W3; N = 128; kmask = 15; kshift = 4; dstoff = W3P_OFF; local = tid - 49152;
    }
    const int lane = local & 63;
    const int tile = local >> 6;
    const int kt = tile & kmask;
    const int nt = tile >> kshift;
    const int k0 = kt * 32 + (lane >> 4) * 8;
    const int n  = nt * 16 + (lane & 15);
    const float* s = src + (size_t)k0 * N + n;
    union { bf16x8 v; short e[8]; } u;
#pragma unroll
    for (int j = 0; j < 8; ++j) u.e[j] = f2bf(s[(size_t)j * N]);
    *((bf16x8*)(wp + dstoff) + local) = u.v;
}

// ---------------------------------------------------------------------------
// Fused kernel. LDS map (64 KiB total, 2 blocks/CU):
//   R0 [0,32768):     X tile bf16 (32 x 256, 512 B/row, swizzled) -> h2 (32 x 512)
//   R1 [32768,65536): h1 bf16 (32 x 512, 1024 B/row, swizzled)   -> y f32 (32 x 132)
// Swizzle: 16B granule index c stored at c ^ (row & 7)  -> conflict-free b128 reads.
// ---------------------------------------------------------------------------
__launch_bounds__(256, 2)
__global__ void fused_mlp(const float* __restrict__ X,
                          const int*   __restrict__ gidx,
                          const short* __restrict__ wp,
                          const float* __restrict__ b1,
                          const float* __restrict__ b2,
                          const float* __restrict__ b3,
                          float* __restrict__ out) {
    __shared__ __align__(16) char lds[65536];
    char* R0 = lds;
    char* R1 = lds + 32768;

    const int t    = threadIdx.x;
    const int lane = t & 63;
    const int wave = t >> 6;
    const int q    = lane >> 4;     // quad 0..3
    const int l15  = lane & 15;
    const int64_t rowBase = (int64_t)blockIdx.x * BM;

    const f32x4 zero4 = {0.f, 0.f, 0.f, 0.f};

    // ---------------- Phase 0: stage X (32 x 256 fp32 -> bf16, swizzled) ----
    {
        const int m  = t >> 3;      // 0..31 row
        const int s  = t & 7;       // col slot
        const int sw = m & 7;
        const float* xr = X + (rowBase + m) * 256;
#pragma unroll
        for (int i = 0; i < 8; ++i) {
            const int col = (s + 8 * i) * 4;           // 4-float chunk
            const float4 f = *(const float4*)(xr + col);
            short4 h;
            h.x = f2bf(f.x); h.y = f2bf(f.y); h.z = f2bf(f.z); h.w = f2bf(f.w);
            const int c = col >> 3;                    // 16B granule
            const int off = m * 512 + ((c ^ sw) << 4) + ((col >> 2) & 1) * 8;
            *(short4*)(R0 + off) = h;
        }
    }
    __syncthreads();

    // ---------------- Phase 1: h1 = relu(X @ W1 + b1)   K=256 -> R1 --------
    {
        f32x4 acc[2][8];
#pragma unroll
        for (int rt = 0; rt < 2; ++rt)
#pragma unroll
            for (int c8 = 0; c8 < 8; ++c8) acc[rt][c8] = zero4;
        const bf16x8* wB = (const bf16x8*)wp;          // W1 packed
        for (int kt = 0; kt < 8; ++kt) {
            bf16x8 a[2];
#pragma unroll
            for (int rt = 0; rt < 2; ++rt) {
                const int m = rt * 16 + l15;
                const int c = kt * 4 + q;
                a[rt] = *(const bf16x8*)(R0 + m * 512 + ((c ^ (m & 7)) << 4));
            }
#pragma unroll
            for (int c8 = 0; c8 < 8; ++c8) {
                const int ct = wave * 8 + c8;
                const bf16x8 b = wB[(ct * 8 + kt) * 64 + lane];
                acc[0][c8] = __builtin_amdgcn_mfma_f32_16x16x32_bf16(a[0], b, acc[0][c8], 0, 0, 0);
                acc[1][c8] = __builtin_amdgcn_mfma_f32_16x16x32_bf16(a[1], b, acc[1][c8], 0, 0, 0);
            }
        }
#pragma unroll
        for (int c8 = 0; c8 < 8; ++c8) {
            const int n = (wave * 8 + c8) * 16 + l15;
            const float bias = b1[n];
            const int cg = n >> 3;
            const int nl = n & 7;
#pragma unroll
            for (int rt = 0; rt < 2; ++rt)
#pragma unroll
                for (int r = 0; r < 4; ++r) {
                    const int m = rt * 16 + q * 4 + r;
                    float v = acc[rt][c8][r] + bias;
                    v = fmaxf(v, 0.f);
                    *(short*)(R1 + m * 1024 + ((cg ^ (m & 7)) << 4) + nl * 2) = f2bf(v);
                }
        }
    }
    __syncthreads();

    // ---------------- Phase 2: h2 = relu(h1 @ W2 + b2)  K=512 -> R0 --------
    {
        f32x4 acc[2][8];
#pragma unroll
        for (int rt = 0; rt < 2; ++rt)
#pragma unroll
            for (int c8 = 0; c8 < 8; ++c8) acc[rt][c8] = zero4;
        const bf16x8* wB = (const bf16x8*)wp + (W2P_OFF >> 3);
        for (int kt = 0; kt < 16; ++kt) {
            bf16x8 a[2];
#pragma unroll
            for (int rt = 0; rt < 2; ++rt) {
                const int m = rt * 16 + l15;
                const int c = kt * 4 + q;
                a[rt] = *(const bf16x8*)(R1 + m * 1024 + ((c ^ (m & 7)) << 4));
            }
#pragma unroll
            for (int c8 = 0; c8 < 8; ++c8) {
                const int ct = wave * 8 + c8;
                const bf16x8 b = wB[(ct * 16 + kt) * 64 + lane];
                acc[0][c8] = __builtin_amdgcn_mfma_f32_16x16x32_bf16(a[0], b, acc[0][c8], 0, 0, 0);
                acc[1][c8] = __builtin_amdgcn_mfma_f32_16x16x32_bf16(a[1], b, acc[1][c8], 0, 0, 0);
            }
        }
#pragma unroll
        for (int c8 = 0; c8 < 8; ++c8) {
            const int n = (wave * 8 + c8) * 16 + l15;
            const float bias = b2[n];
            const int cg = n >> 3;
            const int nl = n & 7;
#pragma unroll
            for (int rt = 0; rt < 2; ++rt)
#pragma unroll
                for (int r = 0; r < 4; ++r) {
                    const int m = rt * 16 + q * 4 + r;
                    float v = acc[rt][c8][r] + bias;
                    v = fmaxf(v, 0.f);
                    *(short*)(R0 + m * 1024 + ((cg ^ (m & 7)) << 4) + nl * 2) = f2bf(v);
                }
        }
    }
    __syncthreads();

    // ---------------- Phase 3: y = silu(h2 @ W3 + b3)   K=512 -> R1 (f32) --
    {
        f32x4 acc[2][2];
#pragma unroll
        for (int rt = 0; rt < 2; ++rt)
#pragma unroll
            for (int c2 = 0; c2 < 2; ++c2) acc[rt][c2] = zero4;
        const bf16x8* wB = (const bf16x8*)wp + (W3P_OFF >> 3);
        for (int kt = 0; kt < 16; ++kt) {
            bf16x8 a[2];
#pragma unroll
            for (int rt = 0; rt < 2; ++rt) {
                const int m = rt * 16 + l15;
                const int c = kt * 4 + q;
                a[rt] = *(const bf16x8*)(R0 + m * 1024 + ((c ^ (m & 7)) << 4));
            }
#pragma unroll
            for (int c2 = 0; c2 < 2; ++c2) {
                const int ct = wave * 2 + c2;
                const bf16x8 b = wB[(ct * 16 + kt) * 64 + lane];
                acc[0][c2] = __builtin_amdgcn_mfma_f32_16x16x32_bf16(a[0], b, acc[0][c2], 0, 0, 0);
                acc[1][c2] = __builtin_amdgcn_mfma_f32_16x16x32_bf16(a[1], b, acc[1][c2], 0, 0, 0);
            }
        }
        float* yl = (float*)R1;                         // 32 x 132 f32 (pad +4)
#pragma unroll
        for (int c2 = 0; c2 < 2; ++c2) {
            const int n = (wave * 2 + c2) * 16 + l15;
            const float bias = b3[n];
#pragma unroll
            for (int rt = 0; rt < 2; ++rt)
#pragma unroll
                for (int r = 0; r < 4; ++r) {
                    const int m = rt * 16 + q * 4 + r;
                    const float yv = acc[rt][c2][r] + bias;
                    const float gv = yv / (1.f + __expf(-yv));   // SiLU
                    yl[m * 132 + n] = gv;
                }
        }
    }
    __syncthreads();

    // ---------------- Phase 4: segmented reduction + global atomics --------
    {
        int* gs = (int*)R0;                             // h2 dead, reuse
        if (t < BM) gs[t] = gidx[rowBase + t];
        __syncthreads();
        const int col = t & 127;
        const int r0  = (t >> 7) * 16;                  // two row-halves
        const float* yl = (const float*)R1;
        int   gprev = gs[r0];
        float acc   = 0.f;
        for (int r = r0; r < r0 + 16; ++r) {
            const int gr = gs[r];
            if (gr != gprev) {
                atomicAdd(out + gprev * N_OUT + col, acc);
                acc = 0.f;
                gprev = gr;
            }
            acc += yl[r * 132 + col];
        }
        atomicAdd(out + gprev * N_OUT + col, acc);
    }
}

extern "C" void kernel_launch(void* const* d_in, const int* in_sizes, int n_in,
                              void* d_out, int out_size, void* d_ws, size_t ws_size,
                              hipStream_t stream) {
    const float* X    = (const float*)d_in[0];
    const int*   gidx = (const int*)  d_in[1];
    const float* W1   = (const float*)d_in[2];
    const float* b1   = (const float*)d_in[3];
    const float* W2   = (const float*)d_in[4];
    const float* b2   = (const float*)d_in[5];
    const float* W3   = (const float*)d_in[6];
    const float* b3   = (const float*)d_in[7];
    float* out = (float*)d_out;
    short* wp  = (short*)d_ws;      // packed bf16 weights, 917504 bytes

    // out is poisoned 0xAA before every timed launch -> zero it (atomic target)
    hipMemsetAsync(d_out, 0, sizeof(float) * N_GRAPHS * N_OUT, stream);

    prepack_weights<<<PREPACK_THREADS / 256, 256, 0, stream>>>(W1, W2, W3, wp);

    fused_mlp<<<N_BLOCKS, 256, 0, stream>>>(X, gidx, wp, b1, b2, b3, out);
}